// Round 3
// baseline (1357.264 us; speedup 1.0000x reference)
//
#include <hip/hip_runtime.h>

typedef unsigned short u16;
typedef short short8 __attribute__((ext_vector_type(8)));
typedef float floatx4 __attribute__((ext_vector_type(4)));

#define B_  2
#define L_  2048
#define D_  1024
#define H_  16
#define HD_ 64
#define M_  (B_*L_)      // 4096 rows
#define WINDOW_ 512
#define DIL_    2

__device__ __forceinline__ float b2f(u16 u) {
    union { unsigned int i; float f; } c; c.i = ((unsigned int)u) << 16; return c.f;
}
__device__ __forceinline__ u16 f2b(float f) {
    union { float f; unsigned int i; } c; c.f = f;
    unsigned int u = c.i;
    u = u + 0x7FFFu + ((u >> 16) & 1u);   // RNE
    return (u16)(u >> 16);
}
// raw-input readers: isbf16 selects interpretation of the raw input buffers
__device__ __forceinline__ float ldrawf(const void* p, size_t i, bool isbf16) {
    return isbf16 ? b2f(((const u16*)p)[i]) : ((const float*)p)[i];
}
__device__ __forceinline__ u16 ldraw16(const void* p, size_t i, bool isbf16) {
    return isbf16 ? ((const u16*)p)[i] : f2b(((const float*)p)[i]);
}

// ---------------- dtype probe on even-indexed u16s of x ----------------
// bf16 data: even u16 = bf16 of N(0,1) sample -> exponent field in [100,140] for ~all.
// fp32 data: even u16 = low mantissa half -> exponent bits ~uniform -> ~16% in range.
__global__ void probe_k(const u16* x, int* flag) {
    int t = threadIdx.x;                        // 0..63
    unsigned int u = x[2 * t];
    unsigned int e = (u >> 7) & 0xFF;
    bool sane = (e >= 100 && e <= 140);
    unsigned long long m = __ballot(sane);
    if (t == 0) *flag = (__popcll(m) >= 32) ? 1 : 0;   // 1 = bf16 inputs
}

// ---------------- weight transpose: in[K,N] -> out[N,K] (bf16 out) ----------------
__global__ __launch_bounds__(256) void transpose_k(const void* __restrict__ in,
                                                   u16* __restrict__ out, int K, int N,
                                                   const int* flagp) {
    bool isb = (*flagp != 0);
    __shared__ u16 tile[32][33];
    int tx = threadIdx.x & 31;
    int ty = threadIdx.x >> 5;            // 0..7
    int nb = blockIdx.x * 32;             // N-base
    int kb = blockIdx.y * 32;             // K-base
    #pragma unroll
    for (int j = 0; j < 32; j += 8)
        tile[ty + j][tx] = ldraw16(in, (size_t)(kb + ty + j) * N + nb + tx, isb);
    __syncthreads();
    #pragma unroll
    for (int j = 0; j < 32; j += 8)
        out[(size_t)(nb + ty + j) * K + kb + tx] = tile[tx][ty + j];
}

// ---------------- LayerNorm (one block per row, D=1024) ----------------
// SRC 0: raw input x (flag-dispatched). SRC 1: fp32 ws buffer.
template<int SRC>
__global__ __launch_bounds__(256) void ln_k(const void* __restrict__ x, const void* __restrict__ g,
                                            const void* __restrict__ bb, u16* __restrict__ out,
                                            const int* flagp) {
    bool isb = (*flagp != 0);
    int row = blockIdx.x;
    int t = threadIdx.x;
    float v[4]; float s = 0.f, s2 = 0.f;
    #pragma unroll
    for (int i = 0; i < 4; i++) {
        size_t idx = (size_t)row * D_ + t + 256 * i;
        float f = (SRC == 1) ? ((const float*)x)[idx] : ldrawf(x, idx, isb);
        v[i] = f; s += f; s2 += f * f;
    }
    #pragma unroll
    for (int off = 32; off >= 1; off >>= 1) { s += __shfl_xor(s, off); s2 += __shfl_xor(s2, off); }
    __shared__ float red[8];
    int wave = t >> 6;
    if ((t & 63) == 0) { red[wave] = s; red[4 + wave] = s2; }
    __syncthreads();
    s  = red[0] + red[1] + red[2] + red[3];
    s2 = red[4] + red[5] + red[6] + red[7];
    float mu  = s * (1.0f / 1024.0f);
    float var = s2 * (1.0f / 1024.0f) - mu * mu;
    float rs  = rsqrtf(var + 1e-5f);
    #pragma unroll
    for (int i = 0; i < 4; i++) {
        int c = t + 256 * i;
        out[(size_t)row * D_ + c] = f2b((v[i] - mu) * rs * ldrawf(g, c, isb) + ldrawf(bb, c, isb));
    }
}

// ---------------- MFMA GEMM: C[M,N] = A[M,K] @ BT[N,K]^T + bias (+gelu)(+resid) ----------------
// 64x64 block tile, BK=32, 4 waves 2x2, each wave 32x32 via 2x2 mfma_f32_16x16x32_bf16.
// A, BT are ws bf16. bias / resid(RES=1) are RAW inputs (flag-dispatched). RES 2: fp32 ws resid.
// OUT: 0 = fp32 ws buffer, 1 = bf16 ws buffer, 2 = d_out (dtype follows input flag).
template<int OUT, int RES, int GELU>
__global__ __launch_bounds__(256) void gemm_k(const u16* __restrict__ A,
                                              const u16* __restrict__ BT,
                                              const void* __restrict__ bias,
                                              const void* __restrict__ resid,
                                              void* __restrict__ C,
                                              int M, int N, int K,
                                              const int* flagp) {
    bool isb = (*flagp != 0);
    __shared__ __align__(16) u16 a_s[64 * 40];   // stride 40 u16 = 80 B
    __shared__ __align__(16) u16 b_s[64 * 40];

    const int bm = blockIdx.y, bn = blockIdx.x;
    const int t = threadIdx.x;
    const int wave = t >> 6, lane = t & 63;
    const int wm = wave >> 1, wn = wave & 1;      // 2x2 wave grid
    const int quad = lane >> 4, r16 = lane & 15;

    const int srow = t >> 2;                      // 0..63
    const int scol = (t & 3) * 8;                 // 0,8,16,24

    floatx4 acc[2][2] = {};

    const u16* Ap  = A  + (size_t)(bm * 64 + srow) * K + scol;
    const u16* BTp = BT + (size_t)(bn * 64 + srow) * K + scol;

    for (int kc = 0; kc < K; kc += 32) {
        int4 av = *(const int4*)(Ap + kc);
        int4 bv = *(const int4*)(BTp + kc);
        __syncthreads();                          // previous iter's frag reads done
        *(int4*)(a_s + srow * 40 + scol) = av;
        *(int4*)(b_s + srow * 40 + scol) = bv;
        __syncthreads();
        short8 af0 = *(const short8*)(a_s + (wm * 32 +      r16) * 40 + quad * 8);
        short8 af1 = *(const short8*)(a_s + (wm * 32 + 16 + r16) * 40 + quad * 8);
        short8 bf0 = *(const short8*)(b_s + (wn * 32 +      r16) * 40 + quad * 8);
        short8 bf1 = *(const short8*)(b_s + (wn * 32 + 16 + r16) * 40 + quad * 8);
        acc[0][0] = __builtin_amdgcn_mfma_f32_16x16x32_bf16(af0, bf0, acc[0][0], 0, 0, 0);
        acc[0][1] = __builtin_amdgcn_mfma_f32_16x16x32_bf16(af0, bf1, acc[0][1], 0, 0, 0);
        acc[1][0] = __builtin_amdgcn_mfma_f32_16x16x32_bf16(af1, bf0, acc[1][0], 0, 0, 0);
        acc[1][1] = __builtin_amdgcn_mfma_f32_16x16x32_bf16(af1, bf1, acc[1][1], 0, 0, 0);
    }

    #pragma unroll
    for (int mt = 0; mt < 2; mt++)
      #pragma unroll
      for (int nt = 0; nt < 2; nt++)
        #pragma unroll
        for (int r = 0; r < 4; r++) {
            int row = bm * 64 + wm * 32 + mt * 16 + quad * 4 + r;
            int col = bn * 64 + wn * 32 + nt * 16 + r16;
            float v = acc[mt][nt][r] + ldrawf(bias, col, isb);
            if (GELU) v = 0.5f * v * (1.0f + erff(v * 0.70710678118654752f));
            if (RES == 1) v += ldrawf(resid, (size_t)row * N + col, isb);
            if (RES == 2) v += ((const float*)resid)[(size_t)row * N + col];
            size_t oi = (size_t)row * N + col;
            if (OUT == 0) ((float*)C)[oi] = v;
            else if (OUT == 1) ((u16*)C)[oi] = f2b(v);
            else { // d_out: dtype follows input dtype
                if (isb) ((u16*)C)[oi] = f2b(v);
                else     ((float*)C)[oi] = v;
            }
        }
}

// ---------------- dilated attention: one wave per (b,h,q), lane = head dim ----------------
__global__ __launch_bounds__(256) void attn_k(const u16* __restrict__ qkv, u16* __restrict__ o) {
    int wid  = blockIdx.x * 4 + (threadIdx.x >> 6);   // 0 .. B*H*L-1
    int lane = threadIdx.x & 63;
    int q  = wid & (L_ - 1);
    int bh = wid >> 11;
    int h  = bh & (H_ - 1);
    int b  = bh >> 4;

    const u16* base = qkv + (size_t)(b * L_) * (3 * D_) + h * HD_ + lane;
    float qd = b2f(base[(size_t)q * (3 * D_)]);

    float m = -INFINITY, l = 0.f, acc = 0.f;
    int jmax = ((q < WINDOW_) ? q : WINDOW_) >> 1;    // delta = 2j, j=0..jmax
    for (int j = 0; j <= jmax; ++j) {
        int kk = q - DIL_ * j;
        const u16* kr = base + (size_t)kk * (3 * D_);
        float kd = b2f(kr[D_]);
        float vd = b2f(kr[2 * D_]);
        float s = qd * kd;
        s += __shfl_xor(s, 32); s += __shfl_xor(s, 16); s += __shfl_xor(s, 8);
        s += __shfl_xor(s, 4);  s += __shfl_xor(s, 2);  s += __shfl_xor(s, 1);
        s *= 0.125f;                                  // 1/sqrt(64)
        float mnew = fmaxf(m, s);
        float fac = __expf(m - mnew);                 // exp(-inf)=0 on first iter
        float p   = __expf(s - mnew);
        l   = l * fac + p;
        acc = acc * fac + p * vd;
        m = mnew;
    }
    o[(size_t)(b * L_ + q) * D_ + h * HD_ + lane] = f2b(acc / l);
}

// ---------------- orchestration ----------------
extern "C" void kernel_launch(void* const* d_in, const int* in_sizes, int n_in,
                              void* d_out, int out_size, void* d_ws, size_t ws_size,
                              hipStream_t stream) {
    (void)in_sizes; (void)n_in; (void)out_size; (void)ws_size;
    const void* x     = d_in[0];
    const void* ln1_g = d_in[1];
    const void* ln1_b = d_in[2];
    const void* Wqkv  = d_in[3];
    const void* bqkv  = d_in[4];
    const void* Wout  = d_in[5];
    const void* bout  = d_in[6];
    const void* ln2_g = d_in[7];
    const void* ln2_b = d_in[8];
    const void* W1    = d_in[9];
    const void* b1    = d_in[10];
    const void* W2    = d_in[11];
    const void* b2    = d_in[12];

    // ---- workspace layout with overlay (total ~72 MB) ----
    // region0 (32MB): [wqkvT 6MB | qkv 24MB | woutT 2MB]  -- all dead after GEMM2
    //                 fbuf (32MB) overlays region0 starting at GEMM3
    char* ws = (char*)d_ws;
    u16*   wqkvT = (u16*)ws;                                   // 3D*D bf16 = 6MB
    u16*   qkv   = (u16*)(ws + (size_t)6  * 1024 * 1024);      // M*3D bf16 = 24MB
    u16*   woutT = (u16*)(ws + (size_t)30 * 1024 * 1024);      // D*D  bf16 = 2MB
    u16*   fbuf  = (u16*)ws;                                   // M*4D bf16 = 32MB (overlay)
    u16*   w1T   = (u16*)(ws + (size_t)32 * 1024 * 1024);      // 4D*D bf16 = 8MB
    u16*   w2T   = (u16*)(ws + (size_t)40 * 1024 * 1024);      // D*4D bf16 = 8MB
    u16*   bufA  = (u16*)(ws + (size_t)48 * 1024 * 1024);      // M*D  bf16 = 8MB
    float* x1    = (float*)(ws + (size_t)56 * 1024 * 1024);    // M*D  f32  = 16MB
    int*   flag  = (int*)(ws + (size_t)72 * 1024 * 1024);

    dim3 tb(256);
    // dtype probe (recomputed every launch)
    probe_k<<<1, 64, 0, stream>>>((const u16*)x, flag);

    // weight transposes ([K,N] -> [N,K] bf16)
    transpose_k<<<dim3(3 * D_ / 32, D_ / 32), tb, 0, stream>>>(Wqkv, wqkvT, D_, 3 * D_, flag);
    transpose_k<<<dim3(D_ / 32, D_ / 32), tb, 0, stream>>>(Wout, woutT, D_, D_, flag);
    transpose_k<<<dim3(4 * D_ / 32, D_ / 32), tb, 0, stream>>>(W1, w1T, D_, 4 * D_, flag);
    transpose_k<<<dim3(D_ / 32, 4 * D_ / 32), tb, 0, stream>>>(W2, w2T, 4 * D_, D_, flag);

    // LN1: x -> h (bufA)
    ln_k<0><<<M_, tb, 0, stream>>>(x, ln1_g, ln1_b, bufA, flag);

    // GEMM1: qkv = h @ Wqkv + bqkv     [4096 x 3072 x 1024]
    gemm_k<1, 0, 0><<<dim3(3 * D_ / 64, M_ / 64), tb, 0, stream>>>(bufA, wqkvT, bqkv, nullptr, qkv, M_, 3 * D_, D_, flag);

    // attention: qkv -> o (bufA)
    attn_k<<<(B_ * H_ * L_) / 4, tb, 0, stream>>>(qkv, bufA);

    // GEMM2: x1 = o @ Wout + bout + x  (fp32 out)   [4096 x 1024 x 1024]
    gemm_k<0, 1, 0><<<dim3(D_ / 64, M_ / 64), tb, 0, stream>>>(bufA, woutT, bout, x, x1, M_, D_, D_, flag);

    // LN2: x1 -> h2 (bufA)
    ln_k<1><<<M_, tb, 0, stream>>>(x1, ln2_g, ln2_b, bufA, flag);

    // GEMM3: f = gelu(h2 @ W1 + b1)    [4096 x 4096 x 1024]  (fbuf overlays dead region0)
    gemm_k<1, 0, 1><<<dim3(4 * D_ / 64, M_ / 64), tb, 0, stream>>>(bufA, w1T, b1, nullptr, fbuf, M_, 4 * D_, D_, flag);

    // GEMM4: out = f @ W2 + b2 + x1    [4096 x 1024 x 4096]  (out dtype = input dtype)
    gemm_k<2, 2, 0><<<dim3(D_ / 64, M_ / 64), tb, 0, stream>>>(fbuf, w2T, b2, x1, d_out, M_, D_, 4 * D_, flag);
}

// Round 4
// 435.158 us; speedup vs baseline: 3.1190x; 3.1190x over previous
//
#include <hip/hip_runtime.h>

typedef unsigned short u16;
typedef short short8 __attribute__((ext_vector_type(8)));
typedef float floatx4 __attribute__((ext_vector_type(4)));

#define B_  2
#define L_  2048
#define D_  1024
#define H_  16
#define HD_ 64
#define M_  (B_*L_)      // 4096 rows
#define LP_ 1024         // compressed (per-parity) seq len
#define WP_ 256          // compressed window

__device__ __forceinline__ float b2f(u16 u) {
    union { unsigned int i; float f; } c; c.i = ((unsigned int)u) << 16; return c.f;
}
__device__ __forceinline__ u16 f2b(float f) {
    union { float f; unsigned int i; } c; c.f = f;
    unsigned int u = c.i;
    u = u + 0x7FFFu + ((u >> 16) & 1u);   // RNE
    return (u16)(u >> 16);
}
__device__ __forceinline__ float ldrawf(const void* p, size_t i, bool isbf16) {
    return isbf16 ? b2f(((const u16*)p)[i]) : ((const float*)p)[i];
}
__device__ __forceinline__ u16 ldraw16(const void* p, size_t i, bool isbf16) {
    return isbf16 ? ((const u16*)p)[i] : f2b(((const float*)p)[i]);
}

// ---------------- dtype probe on even-indexed u16s of x ----------------
__global__ void probe_k(const u16* x, int* flag) {
    int t = threadIdx.x;
    unsigned int u = x[2 * t];
    unsigned int e = (u >> 7) & 0xFF;
    bool sane = (e >= 100 && e <= 140);
    unsigned long long m = __ballot(sane);
    if (t == 0) *flag = (__popcll(m) >= 32) ? 1 : 0;   // 1 = bf16 inputs
}

// ---------------- weight transpose: in[K,N] -> out[N,K] (bf16 out) ----------------
__global__ __launch_bounds__(256) void transpose_k(const void* __restrict__ in,
                                                   u16* __restrict__ out, int K, int N,
                                                   const int* flagp) {
    bool isb = (*flagp != 0);
    __shared__ u16 tile[32][33];
    int tx = threadIdx.x & 31;
    int ty = threadIdx.x >> 5;
    int nb = blockIdx.x * 32;
    int kb = blockIdx.y * 32;
    #pragma unroll
    for (int j = 0; j < 32; j += 8)
        tile[ty + j][tx] = ldraw16(in, (size_t)(kb + ty + j) * N + nb + tx, isb);
    __syncthreads();
    #pragma unroll
    for (int j = 0; j < 32; j += 8)
        out[(size_t)(nb + ty + j) * K + kb + tx] = tile[tx][ty + j];
}

// ---------------- LayerNorm ----------------
template<int SRC>
__global__ __launch_bounds__(256) void ln_k(const void* __restrict__ x, const void* __restrict__ g,
                                            const void* __restrict__ bb, u16* __restrict__ out,
                                            const int* flagp) {
    bool isb = (*flagp != 0);
    int row = blockIdx.x;
    int t = threadIdx.x;
    float v[4]; float s = 0.f, s2 = 0.f;
    #pragma unroll
    for (int i = 0; i < 4; i++) {
        size_t idx = (size_t)row * D_ + t + 256 * i;
        float f = (SRC == 1) ? ((const float*)x)[idx] : ldrawf(x, idx, isb);
        v[i] = f; s += f; s2 += f * f;
    }
    #pragma unroll
    for (int off = 32; off >= 1; off >>= 1) { s += __shfl_xor(s, off); s2 += __shfl_xor(s2, off); }
    __shared__ float red[8];
    int wave = t >> 6;
    if ((t & 63) == 0) { red[wave] = s; red[4 + wave] = s2; }
    __syncthreads();
    s  = red[0] + red[1] + red[2] + red[3];
    s2 = red[4] + red[5] + red[6] + red[7];
    float mu  = s * (1.0f / 1024.0f);
    float var = s2 * (1.0f / 1024.0f) - mu * mu;
    float rs  = rsqrtf(var + 1e-5f);
    #pragma unroll
    for (int i = 0; i < 4; i++) {
        int c = t + 256 * i;
        out[(size_t)row * D_ + c] = f2b((v[i] - mu) * rs * ldrawf(g, c, isb) + ldrawf(bb, c, isb));
    }
}

// ---------------- MFMA GEMM (unchanged from round 3) ----------------
template<int OUT, int RES, int GELU>
__global__ __launch_bounds__(256) void gemm_k(const u16* __restrict__ A,
                                              const u16* __restrict__ BT,
                                              const void* __restrict__ bias,
                                              const void* __restrict__ resid,
                                              void* __restrict__ C,
                                              int M, int N, int K,
                                              const int* flagp) {
    bool isb = (*flagp != 0);
    __shared__ __align__(16) u16 a_s[64 * 40];
    __shared__ __align__(16) u16 b_s[64 * 40];

    const int bm = blockIdx.y, bn = blockIdx.x;
    const int t = threadIdx.x;
    const int wave = t >> 6, lane = t & 63;
    const int wm = wave >> 1, wn = wave & 1;
    const int quad = lane >> 4, r16 = lane & 15;

    const int srow = t >> 2;
    const int scol = (t & 3) * 8;

    floatx4 acc[2][2] = {};

    const u16* Ap  = A  + (size_t)(bm * 64 + srow) * K + scol;
    const u16* BTp = BT + (size_t)(bn * 64 + srow) * K + scol;

    for (int kc = 0; kc < K; kc += 32) {
        int4 av = *(const int4*)(Ap + kc);
        int4 bv = *(const int4*)(BTp + kc);
        __syncthreads();
        *(int4*)(a_s + srow * 40 + scol) = av;
        *(int4*)(b_s + srow * 40 + scol) = bv;
        __syncthreads();
        short8 af0 = *(const short8*)(a_s + (wm * 32 +      r16) * 40 + quad * 8);
        short8 af1 = *(const short8*)(a_s + (wm * 32 + 16 + r16) * 40 + quad * 8);
        short8 bf0 = *(const short8*)(b_s + (wn * 32 +      r16) * 40 + quad * 8);
        short8 bf1 = *(const short8*)(b_s + (wn * 32 + 16 + r16) * 40 + quad * 8);
        acc[0][0] = __builtin_amdgcn_mfma_f32_16x16x32_bf16(af0, bf0, acc[0][0], 0, 0, 0);
        acc[0][1] = __builtin_amdgcn_mfma_f32_16x16x32_bf16(af0, bf1, acc[0][1], 0, 0, 0);
        acc[1][0] = __builtin_amdgcn_mfma_f32_16x16x32_bf16(af1, bf0, acc[1][0], 0, 0, 0);
        acc[1][1] = __builtin_amdgcn_mfma_f32_16x16x32_bf16(af1, bf1, acc[1][1], 0, 0, 0);
    }

    #pragma unroll
    for (int mt = 0; mt < 2; mt++)
      #pragma unroll
      for (int nt = 0; nt < 2; nt++)
        #pragma unroll
        for (int r = 0; r < 4; r++) {
            int row = bm * 64 + wm * 32 + mt * 16 + quad * 4 + r;
            int col = bn * 64 + wn * 32 + nt * 16 + r16;
            float v = acc[mt][nt][r] + ldrawf(bias, col, isb);
            if (GELU) v = 0.5f * v * (1.0f + erff(v * 0.70710678118654752f));
            if (RES == 1) v += ldrawf(resid, (size_t)row * N + col, isb);
            if (RES == 2) v += ((const float*)resid)[(size_t)row * N + col];
            size_t oi = (size_t)row * N + col;
            if (OUT == 0) ((float*)C)[oi] = v;
            else if (OUT == 1) ((u16*)C)[oi] = f2b(v);
            else {
                if (isb) ((u16*)C)[oi] = f2b(v);
                else     ((float*)C)[oi] = v;
            }
        }
}

// ---------------- repack: qkv[M,3D] -> Qp,Kp [pid][l'][64], Vt [pid][64][l'] ----------------
// pid = ((b*2+p)*16 + h), l = 2*l' + p
__global__ __launch_bounds__(256) void repack_k(const u16* __restrict__ qkv,
                                                u16* __restrict__ Qp, u16* __restrict__ Kp,
                                                u16* __restrict__ Vt) {
    int pid = blockIdx.x;            // 0..63
    int lt  = blockIdx.y;            // 0..15, l'-tile of 64
    int b = pid >> 5, p = (pid >> 4) & 1, h = pid & 15;
    int t = threadIdx.x;
    int srow = t >> 2;               // 0..63
    int scol = (t & 3) * 16;         // 0,16,32,48

    int lp = lt * 64 + srow;
    int l  = 2 * lp + p;
    const u16* src = qkv + ((size_t)b * L_ + l) * (3 * D_) + h * HD_;
    size_t dst = ((size_t)pid * LP_ + lp) * HD_;

    *(int4*)(Qp + dst + scol)     = *(const int4*)(src + scol);
    *(int4*)(Qp + dst + scol + 8) = *(const int4*)(src + scol + 8);
    *(int4*)(Kp + dst + scol)     = *(const int4*)(src + D_ + scol);
    *(int4*)(Kp + dst + scol + 8) = *(const int4*)(src + D_ + scol + 8);

    __shared__ u16 vt[64][72];
    *(int4*)(&vt[srow][scol])     = *(const int4*)(src + 2 * D_ + scol);
    *(int4*)(&vt[srow][scol + 8]) = *(const int4*)(src + 2 * D_ + scol + 8);
    __syncthreads();
    // write Vt[pid][d=srow][lt*64 + scol .. +16]
    union { u16 s[16]; int4 v[2]; } tmp;
    #pragma unroll
    for (int jj = 0; jj < 16; jj++) tmp.s[jj] = vt[scol + jj][srow];
    u16* vdst = Vt + ((size_t)pid * HD_ + srow) * LP_ + lt * 64 + scol;
    *(int4*)(vdst)     = tmp.v[0];
    *(int4*)(vdst + 8) = tmp.v[1];
}

// ---------------- flash attention on parity-compressed problems ----------------
// grid (64 pid, 16 qtiles), 256 thr = 4 waves; wave w owns q-rows [q0+w*16, q0+w*16+16)
#define FS 72   // LDS row stride (u16) for 64-col tiles; 144 B (16B-aligned frags)
__global__ __launch_bounds__(256) void fattn_k(const u16* __restrict__ Qp,
                                               const u16* __restrict__ Kp,
                                               const u16* __restrict__ Vt,
                                               u16* __restrict__ o) {
    __shared__ __align__(16) u16 Qs[64 * FS];
    __shared__ __align__(16) u16 Ks[64 * FS];
    __shared__ __align__(16) u16 Vs[64 * FS];
    __shared__ __align__(16) u16 Ps[4][16 * FS];

    const int pid = blockIdx.x, qt = blockIdx.y;
    const int b = pid >> 5, p = (pid >> 4) & 1, h = pid & 15;
    const int t = threadIdx.x, w = t >> 6, lane = t & 63;
    const int quad = lane >> 4, r16 = lane & 15;
    const int q0 = qt * 64;

    const int srow = t >> 2;           // 0..63
    const int scol = (t & 3) * 16;     // 0,16,32,48

    // stage Q tile
    const u16* qsrc = Qp + ((size_t)pid * LP_ + q0 + srow) * HD_;
    *(int4*)(Qs + srow * FS + scol)     = *(const int4*)(qsrc + scol);
    *(int4*)(Qs + srow * FS + scol + 8) = *(const int4*)(qsrc + scol + 8);
    __syncthreads();

    const short8 qf0 = *(const short8*)(Qs + (w * 16 + r16) * FS + quad * 8);
    const short8 qf1 = *(const short8*)(Qs + (w * 16 + r16) * FS + quad * 8 + 32);

    floatx4 oacc[4] = {};
    float mrow[4] = {-INFINITY, -INFINITY, -INFINITY, -INFINITY};
    float lrow[4] = {};

    const int kt0 = (qt >= 4) ? qt - 4 : 0;
    const int qrow_base = q0 + w * 16 + quad * 4;   // + r

    for (int kt = kt0; kt <= qt; ++kt) {
        __syncthreads();
        const u16* ksrc = Kp + ((size_t)pid * LP_ + kt * 64 + srow) * HD_;
        *(int4*)(Ks + srow * FS + scol)     = *(const int4*)(ksrc + scol);
        *(int4*)(Ks + srow * FS + scol + 8) = *(const int4*)(ksrc + scol + 8);
        const u16* vsrc = Vt + ((size_t)pid * HD_ + srow) * LP_ + kt * 64;
        *(int4*)(Vs + srow * FS + scol)     = *(const int4*)(vsrc + scol);
        *(int4*)(Vs + srow * FS + scol + 8) = *(const int4*)(vsrc + scol + 8);
        __syncthreads();

        // S = Q @ K^T   (16q x 64k per wave)
        floatx4 s4[4];
        #pragma unroll
        for (int nt = 0; nt < 4; nt++) {
            short8 kf0 = *(const short8*)(Ks + (nt * 16 + r16) * FS + quad * 8);
            short8 kf1 = *(const short8*)(Ks + (nt * 16 + r16) * FS + quad * 8 + 32);
            floatx4 z = {};
            z = __builtin_amdgcn_mfma_f32_16x16x32_bf16(qf0, kf0, z, 0, 0, 0);
            z = __builtin_amdgcn_mfma_f32_16x16x32_bf16(qf1, kf1, z, 0, 0, 0);
            s4[nt] = z;
        }

        // mask + scale
        float sv[4][4];
        #pragma unroll
        for (int nt = 0; nt < 4; nt++) {
            int kcol = kt * 64 + nt * 16 + r16;
            #pragma unroll
            for (int r = 0; r < 4; r++) {
                int kq = kcol - (qrow_base + r);      // k' - q'
                bool valid = (kq <= 0) && (kq >= -WP_);
                sv[nt][r] = valid ? s4[nt][r] * 0.125f : -1e30f;
            }
        }

        // row max (over nt, then across 16 lanes within quad)
        float mx[4];
        #pragma unroll
        for (int r = 0; r < 4; r++)
            mx[r] = fmaxf(fmaxf(sv[0][r], sv[1][r]), fmaxf(sv[2][r], sv[3][r]));
        #pragma unroll
        for (int off = 8; off >= 1; off >>= 1)
            #pragma unroll
            for (int r = 0; r < 4; r++) mx[r] = fmaxf(mx[r], __shfl_xor(mx[r], off));

        float al[4];
        #pragma unroll
        for (int r = 0; r < 4; r++) {
            float mnew = fmaxf(mrow[r], mx[r]);
            al[r] = __expf(mrow[r] - mnew);           // exp(-inf)=0 first time
            mrow[r] = mnew;
        }

        float ps[4][4], rs[4] = {};
        #pragma unroll
        for (int nt = 0; nt < 4; nt++)
            #pragma unroll
            for (int r = 0; r < 4; r++) {
                float pv = __expf(sv[nt][r] - mrow[r]);
                ps[nt][r] = pv; rs[r] += pv;
            }
        #pragma unroll
        for (int off = 8; off >= 1; off >>= 1)
            #pragma unroll
            for (int r = 0; r < 4; r++) rs[r] += __shfl_xor(rs[r], off);
        #pragma unroll
        for (int r = 0; r < 4; r++) lrow[r] = lrow[r] * al[r] + rs[r];
        #pragma unroll
        for (int nt = 0; nt < 4; nt++)
            #pragma unroll
            for (int r = 0; r < 4; r++) oacc[nt][r] *= al[r];

        // P (C-layout) -> per-wave LDS -> A-layout frags
        #pragma unroll
        for (int nt = 0; nt < 4; nt++)
            #pragma unroll
            for (int r = 0; r < 4; r++)
                Ps[w][(quad * 4 + r) * FS + nt * 16 + r16] = f2b(ps[nt][r]);
        // wave-local: lgkmcnt ordering suffices, no barrier
        short8 pf0 = *(const short8*)(&Ps[w][r16 * FS + quad * 8]);
        short8 pf1 = *(const short8*)(&Ps[w][r16 * FS + quad * 8 + 32]);

        // O += P @ V   (B-frags from Vt rows = V^T[d][k'])
        #pragma unroll
        for (int nt = 0; nt < 4; nt++) {
            short8 vf0 = *(const short8*)(Vs + (nt * 16 + r16) * FS + quad * 8);
            short8 vf1 = *(const short8*)(Vs + (nt * 16 + r16) * FS + quad * 8 + 32);
            oacc[nt] = __builtin_amdgcn_mfma_f32_16x16x32_bf16(pf0, vf0, oacc[nt], 0, 0, 0);
            oacc[nt] = __builtin_amdgcn_mfma_f32_16x16x32_bf16(pf1, vf1, oacc[nt], 0, 0, 0);
        }
    }

    // epilogue: o / l, scatter back to [b][l=2q'+p][h*64+d]
    float inv[4];
    #pragma unroll
    for (int r = 0; r < 4; r++) inv[r] = 1.0f / lrow[r];
    #pragma unroll
    for (int nt = 0; nt < 4; nt++)
        #pragma unroll
        for (int r = 0; r < 4; r++) {
            int qp = qrow_base + r;
            int l  = 2 * qp + p;
            int d  = nt * 16 + r16;
            o[((size_t)b * L_ + l) * D_ + h * HD_ + d] = f2b(oacc[nt][r] * inv[r]);
        }
}

// ---------------- orchestration ----------------
extern "C" void kernel_launch(void* const* d_in, const int* in_sizes, int n_in,
                              void* d_out, int out_size, void* d_ws, size_t ws_size,
                              hipStream_t stream) {
    (void)in_sizes; (void)n_in; (void)out_size; (void)ws_size;
    const void* x     = d_in[0];
    const void* ln1_g = d_in[1];
    const void* ln1_b = d_in[2];
    const void* Wqkv  = d_in[3];
    const void* bqkv  = d_in[4];
    const void* Wout  = d_in[5];
    const void* bout  = d_in[6];
    const void* ln2_g = d_in[7];
    const void* ln2_b = d_in[8];
    const void* W1    = d_in[9];
    const void* b1    = d_in[10];
    const void* W2    = d_in[11];
    const void* b2    = d_in[12];

    char* ws = (char*)d_ws;
    const size_t MB = 1024 * 1024;
    u16*   wqkvT = (u16*)ws;                      // 6MB   [3D, D]
    u16*   qkv   = (u16*)(ws + 6  * MB);          // 24MB  [M, 3D]
    u16*   woutT = (u16*)(ws + 30 * MB);          // 2MB   [D, D]
    u16*   fbuf  = (u16*)ws;                      // 32MB  [M,4D] overlay (GEMM3+)
    u16*   w1T   = (u16*)(ws + 32 * MB);          // 8MB   [4D, D]
    u16*   w2T   = (u16*)(ws + 40 * MB);          // 8MB   [D, 4D]
    u16*   bufA  = (u16*)(ws + 48 * MB);          // 8MB   [M, D]
    float* x1    = (float*)(ws + 56 * MB);        // 16MB  [M, D] f32
    u16*   Qp    = (u16*)(ws + 72 * MB);          // 8MB   [64][1024][64]
    u16*   Kp    = (u16*)(ws + 80 * MB);          // 8MB
    u16*   Vt    = (u16*)(ws + 88 * MB);          // 8MB   [64][64][1024]
    int*   flag  = (int*)(ws + 96 * MB);

    dim3 tb(256);
    probe_k<<<1, 64, 0, stream>>>((const u16*)x, flag);

    transpose_k<<<dim3(3 * D_ / 32, D_ / 32), tb, 0, stream>>>(Wqkv, wqkvT, D_, 3 * D_, flag);
    transpose_k<<<dim3(D_ / 32, D_ / 32), tb, 0, stream>>>(Wout, woutT, D_, D_, flag);
    transpose_k<<<dim3(4 * D_ / 32, D_ / 32), tb, 0, stream>>>(W1, w1T, D_, 4 * D_, flag);
    transpose_k<<<dim3(D_ / 32, 4 * D_ / 32), tb, 0, stream>>>(W2, w2T, 4 * D_, D_, flag);

    ln_k<0><<<M_, tb, 0, stream>>>(x, ln1_g, ln1_b, bufA, flag);

    gemm_k<1, 0, 0><<<dim3(3 * D_ / 64, M_ / 64), tb, 0, stream>>>(bufA, wqkvT, bqkv, nullptr, qkv, M_, 3 * D_, D_, flag);

    repack_k<<<dim3(64, 16), tb, 0, stream>>>(qkv, Qp, Kp, Vt);
    fattn_k<<<dim3(64, 16), tb, 0, stream>>>(Qp, Kp, Vt, bufA);

    gemm_k<0, 1, 0><<<dim3(D_ / 64, M_ / 64), tb, 0, stream>>>(bufA, woutT, bout, x, x1, M_, D_, D_, flag);

    ln_k<1><<<M_, tb, 0, stream>>>(x1, ln2_g, ln2_b, bufA, flag);

    gemm_k<1, 0, 1><<<dim3(4 * D_ / 64, M_ / 64), tb, 0, stream>>>(bufA, w1T, b1, nullptr, fbuf, M_, 4 * D_, D_, flag);

    gemm_k<2, 2, 0><<<dim3(D_ / 64, M_ / 64), tb, 0, stream>>>(fbuf, w2T, b2, x1, d_out, M_, D_, 4 * D_, flag);
}

// Round 5
// 424.169 us; speedup vs baseline: 3.1998x; 1.0259x over previous
//
#include <hip/hip_runtime.h>

typedef unsigned short u16;
typedef short short8 __attribute__((ext_vector_type(8)));
typedef float floatx4 __attribute__((ext_vector_type(4)));

#define B_  2
#define L_  2048
#define D_  1024
#define H_  16
#define HD_ 64
#define M_  (B_*L_)      // 4096 rows
#define LP_ 1024         // compressed (per-parity) seq len
#define WP_ 256          // compressed window

__device__ __forceinline__ float b2f(u16 u) {
    union { unsigned int i; float f; } c; c.i = ((unsigned int)u) << 16; return c.f;
}
__device__ __forceinline__ u16 f2b(float f) {
    union { float f; unsigned int i; } c; c.f = f;
    unsigned int u = c.i;
    u = u + 0x7FFFu + ((u >> 16) & 1u);   // RNE
    return (u16)(u >> 16);
}
__device__ __forceinline__ float ldrawf(const void* p, size_t i, bool isbf16) {
    return isbf16 ? b2f(((const u16*)p)[i]) : ((const float*)p)[i];
}
__device__ __forceinline__ u16 ldraw16(const void* p, size_t i, bool isbf16) {
    return isbf16 ? ((const u16*)p)[i] : f2b(((const float*)p)[i]);
}
// async global->LDS, 16B per lane; LDS dst is wave-uniform base + lane*16
__device__ __forceinline__ void gload16(const u16* g, u16* l) {
    __builtin_amdgcn_global_load_lds(
        (__attribute__((address_space(1))) void*)(g),
        (__attribute__((address_space(3))) void*)(l), 16, 0, 0);
}

// ---------------- dtype probe on even-indexed u16s of x ----------------
__global__ void probe_k(const u16* x, int* flag) {
    int t = threadIdx.x;
    unsigned int u = x[2 * t];
    unsigned int e = (u >> 7) & 0xFF;
    bool sane = (e >= 100 && e <= 140);
    unsigned long long m = __ballot(sane);
    if (t == 0) *flag = (__popcll(m) >= 32) ? 1 : 0;   // 1 = bf16 inputs
}

// ---------------- weight transpose: in[K,N] -> out[N,K] (bf16 out) ----------------
__global__ __launch_bounds__(256) void transpose_k(const void* __restrict__ in,
                                                   u16* __restrict__ out, int K, int N,
                                                   const int* flagp) {
    bool isb = (*flagp != 0);
    __shared__ u16 tile[32][33];
    int tx = threadIdx.x & 31;
    int ty = threadIdx.x >> 5;
    int nb = blockIdx.x * 32;
    int kb = blockIdx.y * 32;
    #pragma unroll
    for (int j = 0; j < 32; j += 8)
        tile[ty + j][tx] = ldraw16(in, (size_t)(kb + ty + j) * N + nb + tx, isb);
    __syncthreads();
    #pragma unroll
    for (int j = 0; j < 32; j += 8)
        out[(size_t)(nb + ty + j) * K + kb + tx] = tile[tx][ty + j];
}

// ---------------- LayerNorm ----------------
template<int SRC>
__global__ __launch_bounds__(256) void ln_k(const void* __restrict__ x, const void* __restrict__ g,
                                            const void* __restrict__ bb, u16* __restrict__ out,
                                            const int* flagp) {
    bool isb = (*flagp != 0);
    int row = blockIdx.x;
    int t = threadIdx.x;
    float v[4]; float s = 0.f, s2 = 0.f;
    #pragma unroll
    for (int i = 0; i < 4; i++) {
        size_t idx = (size_t)row * D_ + t + 256 * i;
        float f = (SRC == 1) ? ((const float*)x)[idx] : ldrawf(x, idx, isb);
        v[i] = f; s += f; s2 += f * f;
    }
    #pragma unroll
    for (int off = 32; off >= 1; off >>= 1) { s += __shfl_xor(s, off); s2 += __shfl_xor(s2, off); }
    __shared__ float red[8];
    int wave = t >> 6;
    if ((t & 63) == 0) { red[wave] = s; red[4 + wave] = s2; }
    __syncthreads();
    s  = red[0] + red[1] + red[2] + red[3];
    s2 = red[4] + red[5] + red[6] + red[7];
    float mu  = s * (1.0f / 1024.0f);
    float var = s2 * (1.0f / 1024.0f) - mu * mu;
    float rs  = rsqrtf(var + 1e-5f);
    #pragma unroll
    for (int i = 0; i < 4; i++) {
        int c = t + 256 * i;
        out[(size_t)row * D_ + c] = f2b((v[i] - mu) * rs * ldrawf(g, c, isb) + ldrawf(bb, c, isb));
    }
}

// ---------------- m97-style MFMA GEMM: C[M,N] = A[M,K] @ BT[N,K]^T ----------------
// 128x(NT*32) block tile, BK=32, 4 waves 2x2, wave = 4x(NT) accs of 16x16x32.
// global_load_lds(16B) staging; XOR k-chunk swizzle to kill LDS bank conflicts.
// OUT: 0 fp32 ws, 1 bf16 ws, 2 d_out (dtype follows flag). RES: 0 none, 1 raw in, 2 fp32 ws.
template<int NT, int OUT, int RES, int GELU>
__global__ __launch_bounds__(256) void gemm128_k(const u16* __restrict__ A,
                                                 const u16* __restrict__ BT,
                                                 const void* __restrict__ bias,
                                                 const void* __restrict__ resid,
                                                 void* __restrict__ C,
                                                 int M, int N, int K,
                                                 const int* flagp) {
    constexpr int TN = NT * 32;                    // 128 or 64
    __shared__ __align__(16) u16 a_s[128 * 32];
    __shared__ __align__(16) u16 b_s[TN * 32];
    bool isb = (*flagp != 0);

    const int bm = blockIdx.y, bn = blockIdx.x;
    const int t = threadIdx.x, w = t >> 6, lane = t & 63;
    const int wm = w >> 1, wn = w & 1;
    const int quad = lane >> 4, r16 = lane & 15;

    // staging: lane -> (row = lr, k-chunk = (lane&3) XOR ((lr>>1)&3)), 16B each
    const int lr  = lane >> 2;                     // 0..15
    const int lcg = (((lane & 3) ^ ((lr >> 1) & 3))) * 8;  // swizzled global k-chunk (u16)
    const u16* Ag0 = A  + (size_t)(bm * 128 + w * 32 + lr) * K + lcg;
    const u16* Ag1 = Ag0 + (size_t)16 * K;
    u16* Al0 = a_s + (w * 32 + lr) * 32 + (lane & 3) * 8;  // physical slot = lane*16B
    u16* Al1 = Al0 + 16 * 32;
    const u16* Bg0 = BT + (size_t)(bn * TN + w * (TN / 4) + lr) * K + lcg;
    const u16* Bg1 = Bg0 + (size_t)16 * K;
    u16* Bl0 = b_s + (w * (TN / 4) + lr) * 32 + (lane & 3) * 8;
    u16* Bl1 = Bl0 + 16 * 32;

    const int sw = ((r16 >> 1) & 3);               // read-side swizzle term
    floatx4 acc[4][NT] = {};

    for (int kc = 0; kc < K; kc += 32) {
        __syncthreads();                           // all waves done reading previous tiles
        gload16(Ag0 + kc, Al0);
        gload16(Ag1 + kc, Al1);
        gload16(Bg0 + kc, Bl0);
        if constexpr (NT == 4) gload16(Bg1 + kc, Bl1);
        __syncthreads();                           // vmcnt(0) drain: tile visible

        short8 af[4], bf[NT];
        #pragma unroll
        for (int mt = 0; mt < 4; mt++)
            af[mt] = *(const short8*)(a_s + (wm * 64 + mt * 16 + r16) * 32 + (quad ^ sw) * 8);
        #pragma unroll
        for (int nt = 0; nt < NT; nt++)
            bf[nt] = *(const short8*)(b_s + (wn * (TN / 2) + nt * 16 + r16) * 32 + (quad ^ sw) * 8);
        #pragma unroll
        for (int mt = 0; mt < 4; mt++)
            #pragma unroll
            for (int nt = 0; nt < NT; nt++)
                acc[mt][nt] = __builtin_amdgcn_mfma_f32_16x16x32_bf16(af[mt], bf[nt], acc[mt][nt], 0, 0, 0);
    }

    #pragma unroll
    for (int mt = 0; mt < 4; mt++)
      #pragma unroll
      for (int nt = 0; nt < NT; nt++)
        #pragma unroll
        for (int r = 0; r < 4; r++) {
            int row = bm * 128 + wm * 64 + mt * 16 + quad * 4 + r;
            int col = bn * TN + wn * (TN / 2) + nt * 16 + r16;
            float v = acc[mt][nt][r] + ldrawf(bias, col, isb);
            if (GELU) v = 0.5f * v * (1.0f + erff(v * 0.70710678118654752f));
            if (RES == 1) v += ldrawf(resid, (size_t)row * N + col, isb);
            if (RES == 2) v += ((const float*)resid)[(size_t)row * N + col];
            size_t oi = (size_t)row * N + col;
            if (OUT == 0) ((float*)C)[oi] = v;
            else if (OUT == 1) ((u16*)C)[oi] = f2b(v);
            else {
                if (isb) ((u16*)C)[oi] = f2b(v);
                else     ((float*)C)[oi] = v;
            }
        }
}

// ---------------- repack: qkv[M,3D] -> Qp,Kp [pid][l'][64], Vt [pid][64][l'] ----------------
__global__ __launch_bounds__(256) void repack_k(const u16* __restrict__ qkv,
                                                u16* __restrict__ Qp, u16* __restrict__ Kp,
                                                u16* __restrict__ Vt) {
    int pid = blockIdx.x;            // 0..63
    int lt  = blockIdx.y;            // 0..15
    int b = pid >> 5, p = (pid >> 4) & 1, h = pid & 15;
    int t = threadIdx.x;
    int srow = t >> 2;
    int scol = (t & 3) * 16;

    int lp = lt * 64 + srow;
    int l  = 2 * lp + p;
    const u16* src = qkv + ((size_t)b * L_ + l) * (3 * D_) + h * HD_;
    size_t dst = ((size_t)pid * LP_ + lp) * HD_;

    *(int4*)(Qp + dst + scol)     = *(const int4*)(src + scol);
    *(int4*)(Qp + dst + scol + 8) = *(const int4*)(src + scol + 8);
    *(int4*)(Kp + dst + scol)     = *(const int4*)(src + D_ + scol);
    *(int4*)(Kp + dst + scol + 8) = *(const int4*)(src + D_ + scol + 8);

    __shared__ u16 vt[64][72];
    *(int4*)(&vt[srow][scol])     = *(const int4*)(src + 2 * D_ + scol);
    *(int4*)(&vt[srow][scol + 8]) = *(const int4*)(src + 2 * D_ + scol + 8);
    __syncthreads();
    union { u16 s[16]; int4 v[2]; } tmp;
    #pragma unroll
    for (int jj = 0; jj < 16; jj++) tmp.s[jj] = vt[scol + jj][srow];
    u16* vdst = Vt + ((size_t)pid * HD_ + srow) * LP_ + lt * 64 + scol;
    *(int4*)(vdst)     = tmp.v[0];
    *(int4*)(vdst + 8) = tmp.v[1];
}

// ---------------- flash attention on parity-compressed problems ----------------
#define FS 72
__global__ __launch_bounds__(256) void fattn_k(const u16* __restrict__ Qp,
                                               const u16* __restrict__ Kp,
                                               const u16* __restrict__ Vt,
                                               u16* __restrict__ o) {
    __shared__ __align__(16) u16 Qs[64 * FS];
    __shared__ __align__(16) u16 Ks[64 * FS];
    __shared__ __align__(16) u16 Vs[64 * FS];
    __shared__ __align__(16) u16 Ps[4][16 * FS];

    const int pid = blockIdx.x, qt = blockIdx.y;
    const int b = pid >> 5, p = (pid >> 4) & 1, h = pid & 15;
    const int t = threadIdx.x, w = t >> 6, lane = t & 63;
    const int quad = lane >> 4, r16 = lane & 15;
    const int q0 = qt * 64;

    const int srow = t >> 2;
    const int scol = (t & 3) * 16;

    const u16* qsrc = Qp + ((size_t)pid * LP_ + q0 + srow) * HD_;
    *(int4*)(Qs + srow * FS + scol)     = *(const int4*)(qsrc + scol);
    *(int4*)(Qs + srow * FS + scol + 8) = *(const int4*)(qsrc + scol + 8);
    __syncthreads();

    const short8 qf0 = *(const short8*)(Qs + (w * 16 + r16) * FS + quad * 8);
    const short8 qf1 = *(const short8*)(Qs + (w * 16 + r16) * FS + quad * 8 + 32);

    floatx4 oacc[4] = {};
    float mrow[4] = {-INFINITY, -INFINITY, -INFINITY, -INFINITY};
    float lrow[4] = {};

    const int kt0 = (qt >= 4) ? qt - 4 : 0;
    const int qrow_base = q0 + w * 16 + quad * 4;

    for (int kt = kt0; kt <= qt; ++kt) {
        __syncthreads();
        const u16* ksrc = Kp + ((size_t)pid * LP_ + kt * 64 + srow) * HD_;
        *(int4*)(Ks + srow * FS + scol)     = *(const int4*)(ksrc + scol);
        *(int4*)(Ks + srow * FS + scol + 8) = *(const int4*)(ksrc + scol + 8);
        const u16* vsrc = Vt + ((size_t)pid * HD_ + srow) * LP_ + kt * 64;
        *(int4*)(Vs + srow * FS + scol)     = *(const int4*)(vsrc + scol);
        *(int4*)(Vs + srow * FS + scol + 8) = *(const int4*)(vsrc + scol + 8);
        __syncthreads();

        floatx4 s4[4];
        #pragma unroll
        for (int nt = 0; nt < 4; nt++) {
            short8 kf0 = *(const short8*)(Ks + (nt * 16 + r16) * FS + quad * 8);
            short8 kf1 = *(const short8*)(Ks + (nt * 16 + r16) * FS + quad * 8 + 32);
            floatx4 z = {};
            z = __builtin_amdgcn_mfma_f32_16x16x32_bf16(qf0, kf0, z, 0, 0, 0);
            z = __builtin_amdgcn_mfma_f32_16x16x32_bf16(qf1, kf1, z, 0, 0, 0);
            s4[nt] = z;
        }

        float sv[4][4];
        #pragma unroll
        for (int nt = 0; nt < 4; nt++) {
            int kcol = kt * 64 + nt * 16 + r16;
            #pragma unroll
            for (int r = 0; r < 4; r++) {
                int kq = kcol - (qrow_base + r);
                bool valid = (kq <= 0) && (kq >= -WP_);
                sv[nt][r] = valid ? s4[nt][r] * 0.125f : -1e30f;
            }
        }

        float mx[4];
        #pragma unroll
        for (int r = 0; r < 4; r++)
            mx[r] = fmaxf(fmaxf(sv[0][r], sv[1][r]), fmaxf(sv[2][r], sv[3][r]));
        #pragma unroll
        for (int off = 8; off >= 1; off >>= 1)
            #pragma unroll
            for (int r = 0; r < 4; r++) mx[r] = fmaxf(mx[r], __shfl_xor(mx[r], off));

        float al[4];
        #pragma unroll
        for (int r = 0; r < 4; r++) {
            float mnew = fmaxf(mrow[r], mx[r]);
            al[r] = __expf(mrow[r] - mnew);
            mrow[r] = mnew;
        }

        float ps[4][4], rs[4] = {};
        #pragma unroll
        for (int nt = 0; nt < 4; nt++)
            #pragma unroll
            for (int r = 0; r < 4; r++) {
                float pv = __expf(sv[nt][r] - mrow[r]);
                ps[nt][r] = pv; rs[r] += pv;
            }
        #pragma unroll
        for (int off = 8; off >= 1; off >>= 1)
            #pragma unroll
            for (int r = 0; r < 4; r++) rs[r] += __shfl_xor(rs[r], off);
        #pragma unroll
        for (int r = 0; r < 4; r++) lrow[r] = lrow[r] * al[r] + rs[r];
        #pragma unroll
        for (int nt = 0; nt < 4; nt++)
            #pragma unroll
            for (int r = 0; r < 4; r++) oacc[nt][r] *= al[r];

        #pragma unroll
        for (int nt = 0; nt < 4; nt++)
            #pragma unroll
            for (int r = 0; r < 4; r++)
                Ps[w][(quad * 4 + r) * FS + nt * 16 + r16] = f2b(ps[nt][r]);
        short8 pf0 = *(const short8*)(&Ps[w][r16 * FS + quad * 8]);
        short8 pf1 = *(const short8*)(&Ps[w][r16 * FS + quad * 8 + 32]);

        #pragma unroll
        for (int nt = 0; nt < 4; nt++) {
            short8 vf0 = *(const short8*)(Vs + (nt * 16 + r16) * FS + quad * 8);
            short8 vf1 = *(const short8*)(Vs + (nt * 16 + r16) * FS + quad * 8 + 32);
            oacc[nt] = __builtin_amdgcn_mfma_f32_16x16x32_bf16(pf0, vf0, oacc[nt], 0, 0, 0);
            oacc[nt] = __builtin_amdgcn_mfma_f32_16x16x32_bf16(pf1, vf1, oacc[nt], 0, 0, 0);
        }
    }

    float inv[4];
    #pragma unroll
    for (int r = 0; r < 4; r++) inv[r] = 1.0f / lrow[r];
    #pragma unroll
    for (int nt = 0; nt < 4; nt++)
        #pragma unroll
        for (int r = 0; r < 4; r++) {
            int qp = qrow_base + r;
            int l  = 2 * qp + p;
            int d  = nt * 16 + r16;
            o[((size_t)b * L_ + l) * D_ + h * HD_ + d] = f2b(oacc[nt][r] * inv[r]);
        }
}

// ---------------- orchestration ----------------
extern "C" void kernel_launch(void* const* d_in, const int* in_sizes, int n_in,
                              void* d_out, int out_size, void* d_ws, size_t ws_size,
                              hipStream_t stream) {
    (void)in_sizes; (void)n_in; (void)out_size; (void)ws_size;
    const void* x     = d_in[0];
    const void* ln1_g = d_in[1];
    const void* ln1_b = d_in[2];
    const void* Wqkv  = d_in[3];
    const void* bqkv  = d_in[4];
    const void* Wout  = d_in[5];
    const void* bout  = d_in[6];
    const void* ln2_g = d_in[7];
    const void* ln2_b = d_in[8];
    const void* W1    = d_in[9];
    const void* b1    = d_in[10];
    const void* W2    = d_in[11];
    const void* b2    = d_in[12];

    char* ws = (char*)d_ws;
    const size_t MB = 1024 * 1024;
    u16*   wqkvT = (u16*)ws;                      // 6MB   [3D, D]
    u16*   qkv   = (u16*)(ws + 6  * MB);          // 24MB  [M, 3D]
    u16*   woutT = (u16*)(ws + 30 * MB);          // 2MB   [D, D]
    u16*   fbuf  = (u16*)ws;                      // 32MB  [M,4D] overlay (GEMM3+)
    u16*   w1T   = (u16*)(ws + 32 * MB);          // 8MB   [4D, D]
    u16*   w2T   = (u16*)(ws + 40 * MB);          // 8MB   [D, 4D]
    u16*   bufA  = (u16*)(ws + 48 * MB);          // 8MB   [M, D]
    float* x1    = (float*)(ws + 56 * MB);        // 16MB  [M, D] f32
    u16*   Qp    = (u16*)(ws + 72 * MB);          // 8MB
    u16*   Kp    = (u16*)(ws + 80 * MB);          // 8MB
    u16*   Vt    = (u16*)(ws + 88 * MB);          // 8MB
    int*   flag  = (int*)(ws + 96 * MB);

    dim3 tb(256);
    probe_k<<<1, 64, 0, stream>>>((const u16*)x, flag);

    transpose_k<<<dim3(3 * D_ / 32, D_ / 32), tb, 0, stream>>>(Wqkv, wqkvT, D_, 3 * D_, flag);
    transpose_k<<<dim3(D_ / 32, D_ / 32), tb, 0, stream>>>(Wout, woutT, D_, D_, flag);
    transpose_k<<<dim3(4 * D_ / 32, D_ / 32), tb, 0, stream>>>(W1, w1T, D_, 4 * D_, flag);
    transpose_k<<<dim3(D_ / 32, 4 * D_ / 32), tb, 0, stream>>>(W2, w2T, 4 * D_, D_, flag);

    ln_k<0><<<M_, tb, 0, stream>>>(x, ln1_g, ln1_b, bufA, flag);

    // GEMM1: qkv = h @ Wqkv + bqkv    [4096 x 3072 x 1024], 128x128 tiles
    gemm128_k<4, 1, 0, 0><<<dim3(3 * D_ / 128, M_ / 128), tb, 0, stream>>>(bufA, wqkvT, bqkv, nullptr, qkv, M_, 3 * D_, D_, flag);

    repack_k<<<dim3(64, 16), tb, 0, stream>>>(qkv, Qp, Kp, Vt);
    fattn_k<<<dim3(64, 16), tb, 0, stream>>>(Qp, Kp, Vt, bufA);

    // GEMM2: x1 = o @ Wout + bout + x  [4096 x 1024 x 1024], 128x64 tiles (512 blocks)
    gemm128_k<2, 0, 1, 0><<<dim3(D_ / 64, M_ / 128), tb, 0, stream>>>(bufA, woutT, bout, x, x1, M_, D_, D_, flag);

    ln_k<1><<<M_, tb, 0, stream>>>(x1, ln2_g, ln2_b, bufA, flag);

    // GEMM3: f = gelu(h2 @ W1 + b1)   [4096 x 4096 x 1024], 128x128 tiles
    gemm128_k<4, 1, 0, 1><<<dim3(4 * D_ / 128, M_ / 128), tb, 0, stream>>>(bufA, w1T, b1, nullptr, fbuf, M_, 4 * D_, D_, flag);

    // GEMM4: out = f @ W2 + b2 + x1   [4096 x 1024 x 4096], 128x64 tiles
    gemm128_k<2, 2, 2, 0><<<dim3(D_ / 64, M_ / 128), tb, 0, stream>>>(fbuf, w2T, b2, x1, d_out, M_, D_, 4 * D_, flag);
}